// Round 4
// baseline (113.811 us; speedup 1.0000x reference)
//
#include <hip/hip_runtime.h>

#define NH 16
#define HD 64
#define LSEQ 2048
#define BQ 128
#define BK 64
#define NQT (LSEQ / BQ)          // 16
#define RS (NH * HD)             // 1024 floats per token row
#define NTILE 4                  // kt = 2qt-1 .. 2qt+2; dropped tiles have weight <= e^-56

#define KSTR 72                  // sK row stride (elements): b64 stores conflict-free, b128 reads 2-way
#define VSTR 74                  // sVt row stride: store bank step 20 mod 32 -> 2-way (was 16 -> 8-way)
#define PSTR 72                  // sP row stride: analyzed ~2-way on both sides

typedef __bf16 bf16x8 __attribute__((ext_vector_type(8)));
typedef __bf16 bf16x4 __attribute__((ext_vector_type(4)));
typedef float f32x4 __attribute__((ext_vector_type(4)));

// exp(-8): fixed softmax shift folded into the mask multiplier; cancels in O/l.
#define EXP_NEG8 0.00033546262790251185f

__global__ __launch_bounds__(512, 4)
void attn_kernel(const float* __restrict__ Q,
                 const float* __restrict__ K,
                 const float* __restrict__ V,
                 const int* __restrict__ Mk,
                 float* __restrict__ Out)
{
    // [K0|K1|V0|V1]; reused after the loop as float oscr[128][64] (32768 B <= 37376 B).
    __shared__ alignas(16) char smem_raw[(2 * BK * KSTR + 2 * HD * VSTR) * 2];
    __shared__ alignas(16) __bf16 sP[8][16][PSTR];
    __bf16* kvb = (__bf16*)smem_raw;

    const int tid  = threadIdx.x;
    const int wave = tid >> 6;
    const int lane = tid & 63;
    const int ln   = lane & 15;
    const int quad = lane >> 4;

    const int qt = blockIdx.x & (NQT - 1);
    const int bh = blockIdx.x >> 4;
    const int b  = bh >> 4;
    const int h  = bh & 15;

    const int q0   = qt * BQ;
    const int qrow = q0 + wave * 16;

    const size_t bh_off = ((size_t)b * LSEQ) * RS + (size_t)h * HD;
    const float* gQ = Q + bh_off;
    const float* gK = K + bh_off;
    const float* gV = V + bh_off;
    const int*   gM = Mk + (size_t)b * LSEQ;
    float*       gO = Out + bh_off;

    // staging map: idx = tid + i*512 -> (row 0..63, 16B chunk 0..15)
    int srow[2], sc4[2];
#pragma unroll
    for (int i = 0; i < 2; ++i) { int idx = tid + i * 512; srow[i] = idx >> 4; sc4[i] = idx & 15; }

    // ---- Q fragments (A-operand), pre-scaled by 1/sqrt(D)
    bf16x8 qfrag[2];
#pragma unroll
    for (int c = 0; c < 2; ++c) {
        const float* src = gQ + (size_t)(qrow + ln) * RS + c * 32 + quad * 8;
        float4 f0 = *(const float4*)(src);
        float4 f1 = *(const float4*)(src + 4);
        bf16x8 t;
        t[0] = (__bf16)(f0.x * 0.125f); t[1] = (__bf16)(f0.y * 0.125f);
        t[2] = (__bf16)(f0.z * 0.125f); t[3] = (__bf16)(f0.w * 0.125f);
        t[4] = (__bf16)(f1.x * 0.125f); t[5] = (__bf16)(f1.y * 0.125f);
        t[6] = (__bf16)(f1.z * 0.125f); t[7] = (__bf16)(f1.w * 0.125f);
        qfrag[c] = t;
    }

    f32x4 o_acc[4];
#pragma unroll
    for (int i = 0; i < 4; ++i) o_acc[i] = f32x4{0.f, 0.f, 0.f, 0.f};
    float l_part[4] = {0.f, 0.f, 0.f, 0.f};

    int k0s[NTILE];
#pragma unroll
    for (int j = 0; j < NTILE; ++j) k0s[j] = ((2 * qt + 31 + j) & 31) * BK;

    float4 kreg[2], vreg[2];
    int mr[4];
#pragma unroll
    for (int i = 0; i < 2; ++i) {
        kreg[i] = *(const float4*)(gK + (size_t)(k0s[0] + srow[i]) * RS + sc4[i] * 4);
        vreg[i] = *(const float4*)(gV + (size_t)(k0s[0] + srow[i]) * RS + sc4[i] * 4);
    }
#pragma unroll
    for (int t = 0; t < 4; ++t) mr[t] = gM[k0s[0] + t * 16 + ln];

#pragma unroll
    for (int j = 0; j < NTILE; ++j) {
        const int bb = j & 1;
        __bf16* sKb = kvb + bb * (BK * KSTR);                  // [64][KSTR]
        __bf16* sVb = kvb + 2 * BK * KSTR + bb * (HD * VSTR);  // [64][VSTR], V transposed [d][k]

        // ---- store prefetched tile into this iter's buffer ----
#pragma unroll
        for (int i = 0; i < 2; ++i) {
            float4 f = kreg[i];
            bf16x4 kk;
            kk[0] = (__bf16)f.x; kk[1] = (__bf16)f.y;
            kk[2] = (__bf16)f.z; kk[3] = (__bf16)f.w;
            *(bf16x4*)(sKb + srow[i] * KSTR + sc4[i] * 4) = kk;   // one b64, conflict-free
            float4 g = vreg[i];
            sVb[(sc4[i] * 4 + 0) * VSTR + srow[i]] = (__bf16)g.x;
            sVb[(sc4[i] * 4 + 1) * VSTR + srow[i]] = (__bf16)g.y;
            sVb[(sc4[i] * 4 + 2) * VSTR + srow[i]] = (__bf16)g.z;
            sVb[(sc4[i] * 4 + 3) * VSTR + srow[i]] = (__bf16)g.w;
        }
        float mm[4];
#pragma unroll
        for (int t = 0; t < 4; ++t) mm[t] = mr[t] ? EXP_NEG8 : 0.f;

        // ---- prefetch next tile ----
        if (j + 1 < NTILE) {
            const int k0n = k0s[j + 1];
#pragma unroll
            for (int i = 0; i < 2; ++i) {
                kreg[i] = *(const float4*)(gK + (size_t)(k0n + srow[i]) * RS + sc4[i] * 4);
                vreg[i] = *(const float4*)(gV + (size_t)(k0n + srow[i]) * RS + sc4[i] * 4);
            }
#pragma unroll
            for (int t = 0; t < 4; ++t) mr[t] = gM[k0n + t * 16 + ln];
        }
        __syncthreads();   // single barrier per tile (double-buffered K/V)

        // ---- S = Q K^T ----
        const int k0 = k0s[j];
        f32x4 s[4];
#pragma unroll
        for (int t = 0; t < 4; ++t) {
            f32x4 acc = f32x4{0.f, 0.f, 0.f, 0.f};
#pragma unroll
            for (int ch = 0; ch < 2; ++ch) {
                bf16x8 bk = *(const bf16x8*)(sKb + (t * 16 + ln) * KSTR + ch * 32 + quad * 8);
                acc = __builtin_amdgcn_mfma_f32_16x16x32_bf16(qfrag[ch], bk, acc, 0, 0, 0);
            }
            s[t] = acc;
        }

        // ---- fixed-shift softmax: p = exp(s - d) * (mask ? e^-8 : 0); no reductions ----
        const int qg0 = qrow + quad * 4;
#pragma unroll
        for (int t = 0; t < 4; ++t) {
            const int kg = k0 + t * 16 + ln;
#pragma unroll
            for (int r = 0; r < 4; ++r) {
                int dd = qg0 + r - kg; dd = dd < 0 ? -dd : dd;
                int d2 = LSEQ - dd; dd = d2 < dd ? d2 : dd;
                float p = __expf(s[t][r] - (float)dd) * mm[t];
                l_part[r] += p;
                sP[wave][quad * 4 + r][t * 16 + ln] = (__bf16)p;
            }
        }

        // ---- O += P V ----
#pragma unroll
        for (int ch = 0; ch < 2; ++ch) {
            bf16x8 pa = *(const bf16x8*)&sP[wave][ln][ch * 32 + quad * 8];
#pragma unroll
            for (int nt = 0; nt < 4; ++nt) {
                bf16x8 bv = *(const bf16x8*)(sVb + (nt * 16 + ln) * VSTR + ch * 32 + quad * 8);
                o_acc[nt] = __builtin_amdgcn_mfma_f32_16x16x32_bf16(pa, bv, o_acc[nt], 0, 0, 0);
            }
        }
        // no trailing barrier: next iter writes the other buffer; its barrier orders reuse.
    }

    // ---- epilogue: reduce l (once), divide, coalesced float4 stores via LDS ----
    float inv[4];
#pragma unroll
    for (int r = 0; r < 4; ++r) {
        float l = l_part[r];
#pragma unroll
        for (int off = 1; off < 16; off <<= 1)
            l += __shfl_xor(l, off, 64);
        inv[r] = 1.f / l;
    }

    __syncthreads();   // everyone done reading K/V buffers
    float* oscr = (float*)smem_raw;    // [128][64]
#pragma unroll
    for (int r = 0; r < 4; ++r)
#pragma unroll
        for (int nt = 0; nt < 4; ++nt)
            oscr[(wave * 16 + quad * 4 + r) * 64 + nt * 16 + ln] = o_acc[nt][r] * inv[r];
    __syncthreads();

#pragma unroll
    for (int p = 0; p < 4; ++p) {
        int f   = tid + p * 512;
        int row = f >> 4;
        int c4  = f & 15;
        float4 val = *(const float4*)&oscr[row * 64 + c4 * 4];
        *(float4*)(gO + (size_t)(q0 + row) * RS + c4 * 4) = val;
    }
}

extern "C" void kernel_launch(void* const* d_in, const int* in_sizes, int n_in,
                              void* d_out, int out_size, void* d_ws, size_t ws_size,
                              hipStream_t stream) {
    const float* Q  = (const float*)d_in[0];
    const float* K  = (const float*)d_in[1];
    const float* V  = (const float*)d_in[2];
    const int*   Mk = (const int*)d_in[3];
    float*       O  = (float*)d_out;

    dim3 grid(2 * NH * NQT);   // 512 blocks
    dim3 block(512);
    attn_kernel<<<grid, block, 0, stream>>>(Q, K, V, Mk, O);
}

// Round 5
// 113.774 us; speedup vs baseline: 1.0003x; 1.0003x over previous
//
#include <hip/hip_runtime.h>

#define NH 16
#define HD 64
#define LSEQ 2048
#define BQ 128
#define BK 64
#define NQT (LSEQ / BQ)          // 16
#define RS (NH * HD)             // 1024 floats per token row
#define NTILE 4                  // kt = 2qt-1 .. 2qt+2: minimal band (edge queries get +-64)

#define KSTR 72                  // b64 stores ~free; b128 reads 2-way (4ln bank step)
#define VSTR 74                  // scatter b16 stores 2-way (bank step 20); b128 reads ~2-way
#define PSTR 72                  // b64 stores 2-way; b128 reads 2-way

typedef __bf16 bf16x8 __attribute__((ext_vector_type(8)));
typedef __bf16 bf16x4 __attribute__((ext_vector_type(4)));
typedef float f32x4 __attribute__((ext_vector_type(4)));

// exp(-8): fixed softmax shift folded into the mask multiplier; cancels in O/l.
#define EXP_NEG8 0.00033546262790251185f

__global__ __launch_bounds__(512, 4)
void attn_kernel(const float* __restrict__ Q,
                 const float* __restrict__ K,
                 const float* __restrict__ V,
                 const int* __restrict__ Mk,
                 float* __restrict__ Out)
{
    __shared__ alignas(16) __bf16 sK[2][BK][KSTR];    // 18432 B
    __shared__ alignas(16) __bf16 sVt[2][HD][VSTR];   // 18944 B, V transposed [d][k]
    __shared__ alignas(16) __bf16 sPT[8][16][PSTR];   // 18432 B, P^T per wave: [q][k]

    const int tid  = threadIdx.x;
    const int wave = tid >> 6;
    const int lane = tid & 63;
    const int ln   = lane & 15;
    const int quad = lane >> 4;

    const int qt = blockIdx.x & (NQT - 1);
    const int bh = blockIdx.x >> 4;
    const int b  = bh >> 4;
    const int h  = bh & 15;

    const int q0   = qt * BQ;
    const int qrow = q0 + wave * 16;

    const size_t bh_off = ((size_t)b * LSEQ) * RS + (size_t)h * HD;
    const float* gQ = Q + bh_off;
    const float* gK = K + bh_off;
    const float* gV = V + bh_off;
    const int*   gM = Mk + (size_t)b * LSEQ;
    float*       gO = Out + bh_off;

    // staging map: idx = tid + i*512 -> (row 0..63, 16B chunk 0..15)
    int srow[2], sc4[2];
#pragma unroll
    for (int i = 0; i < 2; ++i) { int idx = tid + i * 512; srow[i] = idx >> 4; sc4[i] = idx & 15; }

    // ---- Q fragments, pre-scaled by 1/sqrt(D). Serve as the B-operand of S^T = K Q^T:
    // B[k=d][n=q]: lane holds n=ln -> Q[qrow+ln][quad*8+j]  (same load as before).
    bf16x8 qfrag[2];
#pragma unroll
    for (int c = 0; c < 2; ++c) {
        const float* src = gQ + (size_t)(qrow + ln) * RS + c * 32 + quad * 8;
        float4 f0 = *(const float4*)(src);
        float4 f1 = *(const float4*)(src + 4);
        bf16x8 t;
        t[0] = (__bf16)(f0.x * 0.125f); t[1] = (__bf16)(f0.y * 0.125f);
        t[2] = (__bf16)(f0.z * 0.125f); t[3] = (__bf16)(f0.w * 0.125f);
        t[4] = (__bf16)(f1.x * 0.125f); t[5] = (__bf16)(f1.y * 0.125f);
        t[6] = (__bf16)(f1.z * 0.125f); t[7] = (__bf16)(f1.w * 0.125f);
        qfrag[c] = t;
    }

    f32x4 o_acc[4];   // O^T C-layout: lane holds O[q=qrow+ln][d=nt*16+quad*4+r]
#pragma unroll
    for (int i = 0; i < 4; ++i) o_acc[i] = f32x4{0.f, 0.f, 0.f, 0.f};
    float l_sum = 0.f;   // per-lane: sum of p for q=qrow+ln over this quad's k rows

    int k0s[NTILE];
#pragma unroll
    for (int j = 0; j < NTILE; ++j) k0s[j] = ((2 * qt + 31 + j) & 31) * BK;

    float4 kreg[2], vreg[2];
    int4 mnext[4];   // masks for k = k0 + t*16 + quad*4 + {0..3}
#pragma unroll
    for (int i = 0; i < 2; ++i) {
        kreg[i] = *(const float4*)(gK + (size_t)(k0s[0] + srow[i]) * RS + sc4[i] * 4);
        vreg[i] = *(const float4*)(gV + (size_t)(k0s[0] + srow[i]) * RS + sc4[i] * 4);
    }
#pragma unroll
    for (int t = 0; t < 4; ++t) mnext[t] = *(const int4*)(gM + k0s[0] + t * 16 + quad * 4);

#pragma unroll
    for (int j = 0; j < NTILE; ++j) {
        const int bb = j & 1;
        const int k0 = k0s[j];

        // ---- store prefetched tile ----
#pragma unroll
        for (int i = 0; i < 2; ++i) {
            float4 f = kreg[i];
            bf16x4 kk;
            kk[0] = (__bf16)f.x; kk[1] = (__bf16)f.y;
            kk[2] = (__bf16)f.z; kk[3] = (__bf16)f.w;
            *(bf16x4*)&sK[bb][srow[i]][sc4[i] * 4] = kk;
            float4 g = vreg[i];
            sVt[bb][sc4[i] * 4 + 0][srow[i]] = (__bf16)g.x;
            sVt[bb][sc4[i] * 4 + 1][srow[i]] = (__bf16)g.y;
            sVt[bb][sc4[i] * 4 + 2][srow[i]] = (__bf16)g.z;
            sVt[bb][sc4[i] * 4 + 3][srow[i]] = (__bf16)g.w;
        }
        float mf[4][4];
#pragma unroll
        for (int t = 0; t < 4; ++t) {
            mf[t][0] = mnext[t].x ? EXP_NEG8 : 0.f;
            mf[t][1] = mnext[t].y ? EXP_NEG8 : 0.f;
            mf[t][2] = mnext[t].z ? EXP_NEG8 : 0.f;
            mf[t][3] = mnext[t].w ? EXP_NEG8 : 0.f;
        }

        // ---- prefetch next tile ----
        if (j + 1 < NTILE) {
            const int k0n = k0s[j + 1];
#pragma unroll
            for (int i = 0; i < 2; ++i) {
                kreg[i] = *(const float4*)(gK + (size_t)(k0n + srow[i]) * RS + sc4[i] * 4);
                vreg[i] = *(const float4*)(gV + (size_t)(k0n + srow[i]) * RS + sc4[i] * 4);
            }
#pragma unroll
            for (int t = 0; t < 4; ++t) mnext[t] = *(const int4*)(gM + k0n + t * 16 + quad * 4);
        }
        __syncthreads();   // single barrier per tile

        // ---- S^T = K Q^T: C-layout row = k-sub = quad*4+r, col = q = ln ----
        f32x4 st[4];
#pragma unroll
        for (int t = 0; t < 4; ++t) {
            f32x4 acc = f32x4{0.f, 0.f, 0.f, 0.f};
#pragma unroll
            for (int ch = 0; ch < 2; ++ch) {
                bf16x8 kf = *(const bf16x8*)&sK[bb][t * 16 + ln][ch * 32 + quad * 8];
                acc = __builtin_amdgcn_mfma_f32_16x16x32_bf16(kf, qfrag[ch], acc, 0, 0, 0);
            }
            st[t] = acc;
        }

        // ---- fixed-shift softmax; P^T stored k-contiguous (one b64 per block) ----
        const int qg = qrow + ln;
#pragma unroll
        for (int t = 0; t < 4; ++t) {
            bf16x4 pt;
#pragma unroll
            for (int r = 0; r < 4; ++r) {
                int kg = k0 + t * 16 + quad * 4 + r;
                int dd = qg - kg; dd = dd < 0 ? -dd : dd;
                int d2 = LSEQ - dd; dd = d2 < dd ? d2 : dd;
                float p = __expf(st[t][r] - (float)dd) * mf[t][r];
                l_sum += p;
                pt[r] = (__bf16)p;
            }
            *(bf16x4*)&sPT[wave][ln][t * 16 + quad * 4] = pt;
        }

        // ---- O^T += V^T P^T ----
#pragma unroll
        for (int ch = 0; ch < 2; ++ch) {
            bf16x8 pb = *(const bf16x8*)&sPT[wave][ln][ch * 32 + quad * 8];
#pragma unroll
            for (int nt = 0; nt < 4; ++nt) {
                bf16x8 vf = *(const bf16x8*)&sVt[bb][nt * 16 + ln][ch * 32 + quad * 8];
                o_acc[nt] = __builtin_amdgcn_mfma_f32_16x16x32_bf16(vf, pb, o_acc[nt], 0, 0, 0);
            }
        }
        // no trailing barrier: next iter writes the other K/V buffer; its barrier orders reuse.
    }

    // ---- epilogue: reduce l across quads (2 shuffles), direct coalesced float4 stores ----
    float l = l_sum;
    l += __shfl_xor(l, 16, 64);
    l += __shfl_xor(l, 32, 64);
    const float inv = 1.f / l;

    float* dst = gO + (size_t)(qrow + ln) * RS + quad * 4;
#pragma unroll
    for (int nt = 0; nt < 4; ++nt) {
        float4 ov;
        ov.x = o_acc[nt][0] * inv;
        ov.y = o_acc[nt][1] * inv;
        ov.z = o_acc[nt][2] * inv;
        ov.w = o_acc[nt][3] * inv;
        *(float4*)(dst + nt * 16) = ov;   // 4 quads x 16B tile a 64B row segment
    }
}

extern "C" void kernel_launch(void* const* d_in, const int* in_sizes, int n_in,
                              void* d_out, int out_size, void* d_ws, size_t ws_size,
                              hipStream_t stream) {
    const float* Q  = (const float*)d_in[0];
    const float* K  = (const float*)d_in[1];
    const float* V  = (const float*)d_in[2];
    const int*   Mk = (const int*)d_in[3];
    float*       O  = (float*)d_out;

    dim3 grid(2 * NH * NQT);   // 512 blocks
    dim3 block(512);
    attn_kernel<<<grid, block, 0, stream>>>(Q, K, V, Mk, O);
}